// Round 6
// baseline (212.669 us; speedup 1.0000x reference)
//
#include <hip/hip_runtime.h>

#define F 128
#define TILE 16
#define NTHR 256

typedef __attribute__((ext_vector_type(8))) __bf16 bf16x8;
typedef __attribute__((ext_vector_type(4))) float f32x4;
typedef __attribute__((ext_vector_type(8))) unsigned short us8;
typedef __attribute__((ext_vector_type(4))) unsigned short us4;
typedef __attribute__((ext_vector_type(2))) unsigned short us2;

struct f3 { float x, y, z; };   // 12B -> global_store_dwordx3

__device__ __forceinline__ unsigned short f2bf(float x) {
    __bf16 h = (__bf16)x;                       // HW v_cvt (RNE)
    return __builtin_bit_cast(unsigned short, h);
}
__device__ __forceinline__ float bf2f(unsigned short u) {
    unsigned x = ((unsigned)u) << 16;
    return __builtin_bit_cast(float, x);
}
__device__ __forceinline__ bf16x8 pack8(float4 a, float4 b) {
    us8 t;
    t[0] = f2bf(a.x); t[1] = f2bf(a.y); t[2] = f2bf(a.z); t[3] = f2bf(a.w);
    t[4] = f2bf(b.x); t[5] = f2bf(b.y); t[6] = f2bf(b.z); t[7] = f2bf(b.w);
    return __builtin_bit_cast(bf16x8, t);
}

// async global->LDS, 16B per lane; lds base wave-uniform
__device__ __forceinline__ void gload16(const float* g, const unsigned short* l) {
    __builtin_amdgcn_global_load_lds(
        (const __attribute__((address_space(1))) void*)g,
        (__attribute__((address_space(3))) void*)l, 16, 0, 0);
}

// LDS map (ushort units), 25216 sh = 50432 B -> 3 blocks/CU (151296 <= 163840)
#define RAWV 0        // 12288 sh : raw f32 v tile (16x128x3), linear
#define A1B  12288    // 48 x 136 : v bf16, row m = c*16+nl
#define A1S  136
#define A2B  18816    // 16 x 264 : s bf16 | ||Vv||^2 bf16
#define A2S  264
#define A3B  23040    // 16 x 136 : h bf16
#define A3S  136
#define SHSZ 25216

__global__ __launch_bounds__(256)
void prep_w(const float* __restrict__ Uw, const float* __restrict__ Vw,
            const float* __restrict__ aw1, const float* __restrict__ aw2,
            unsigned short* __restrict__ wbf)
{
    int i = (blockIdx.x * 256 + threadIdx.x) * 4;   // grid 112x256 covers 114688
    const float* src; int off;
    if (i < 16384)      { src = Uw;  off = i; }
    else if (i < 32768) { src = Vw;  off = i - 16384; }
    else if (i < 65536) { src = aw1; off = i - 32768; }
    else                { src = aw2; off = i - 65536; }
    float4 x = *(const float4*)&src[off];
    us4 o;
    o[0] = f2bf(x.x); o[1] = f2bf(x.y); o[2] = f2bf(x.z); o[3] = f2bf(x.w);
    *(us4*)&wbf[i] = o;
}

template<bool PRE>
__global__ __launch_bounds__(NTHR) __attribute__((amdgpu_waves_per_eu(3)))
void painn_main(const float* __restrict__ s, const float* __restrict__ v,
                const float* __restrict__ Uw, const float* __restrict__ Vw,
                const float* __restrict__ aw1, const float* __restrict__ ab1,
                const float* __restrict__ aw2, const float* __restrict__ ab2,
                const unsigned short* __restrict__ wbf,
                float* __restrict__ out, int Ntot)
{
    __shared__ __align__(16) unsigned short SH[SHSZ];

    const int tid  = threadIdx.x;
    const int lane = tid & 63;
    const int w    = tid >> 6;        // wave 0..3
    const int l15  = lane & 15;
    const int kp   = lane >> 4;       // 0..3
    const int colA = (w << 4) | l15;        // columns this lane owns
    const int colB = 64 + ((w << 4) | l15);
    const size_t NF = (size_t)Ntot * F;
    const int t    = blockIdx.x;            // one 16-row tile per block

    const unsigned short* wU  = wbf;
    const unsigned short* wV  = wbf + 16384;
    const unsigned short* wW1 = wbf + 32768;
    const unsigned short* wW2 = wbf + 65536;

    const int vf0  = lane << 1;          // f-pair this lane converts for v
    const int srow = tid >> 4;           // s row 0..15
    const int sf0  = (tid & 15) << 3;    // s f-offset (8 floats)

    const float* rawv = (const float*)&SH[RAWV];

    // ---- issue all front-loaded vmem: s regs, stage-1 weights, then asyncs ----
    float4 sp0, sp1;
    {
        const float* ssrc = s + (size_t)t * TILE * 128 + srow * 128 + sf0;
        sp0 = *(const float4*)ssrc;
        sp1 = *(const float4*)(ssrc + 4);
    }
    bf16x8 bU[2][4], bV[2][4];
    #pragma unroll
    for (int g = 0; g < 2; ++g) {
        int colg = g ? colB : colA;
        #pragma unroll
        for (int ks = 0; ks < 4; ++ks) {
            int k0 = (ks << 5) + (kp << 3);
            if constexpr (PRE) {
                bU[g][ks] = *(const bf16x8*)&wU[colg * F + k0];
                bV[g][ks] = *(const bf16x8*)&wV[colg * F + k0];
            } else {
                const float4* pu = (const float4*)&Uw[colg * F + k0];
                bU[g][ks] = pack8(pu[0], pu[1]);
                const float4* pv = (const float4*)&Vw[colg * F + k0];
                bV[g][ks] = pack8(pv[0], pv[1]);
            }
        }
    }
    {
        const float* vsrc = v + (size_t)t * TILE * 384;
        #pragma unroll
        for (int j = 0; j < 6; ++j) {
            int ofs = (w + j * 4) * 256;                  // floats; 1024B per wave-round
            gload16(vsrc + ofs + lane * 4, &SH[RAWV + ofs * 2]);
        }
    }
    asm volatile("s_waitcnt vmcnt(0)" ::: "memory");
    __builtin_amdgcn_s_barrier();                         // rawv + regs ready

    // ---- convert: raw f32 -> A1 (v bf16, c-major rows); s regs -> A2 s-half ----
    #pragma unroll
    for (int it = 0; it < 4; ++it) {
        int idx = tid + it * 256;
        int nl  = idx >> 6;               // 0..15
        int f0  = (idx & 63) << 1;
        const float2* src = (const float2*)&rawv[nl * 384 + f0 * 3];
        float2 ab = src[0], cd = src[1], ef = src[2];
        us2 p;
        p[0] = f2bf(ab.x); p[1] = f2bf(cd.y); *(us2*)&SH[A1B + (0 * TILE + nl) * A1S + f0] = p;
        p[0] = f2bf(ab.y); p[1] = f2bf(ef.x); *(us2*)&SH[A1B + (1 * TILE + nl) * A1S + f0] = p;
        p[0] = f2bf(cd.x); p[1] = f2bf(ef.y); *(us2*)&SH[A1B + (2 * TILE + nl) * A1S + f0] = p;
    }
    {
        us4 t0, t1;
        t0[0] = f2bf(sp0.x); t0[1] = f2bf(sp0.y); t0[2] = f2bf(sp0.z); t0[3] = f2bf(sp0.w);
        t1[0] = f2bf(sp1.x); t1[1] = f2bf(sp1.y); t1[2] = f2bf(sp1.z); t1[3] = f2bf(sp1.w);
        *(us4*)&SH[A2B + srow * A2S + sf0]     = t0;
        *(us4*)&SH[A2B + srow * A2S + sf0 + 4] = t1;
    }
    asm volatile("s_waitcnt lgkmcnt(0)" ::: "memory");
    __builtin_amdgcn_s_barrier();                         // B1: A1 + A2 s-half ready

    // ---- stage 1: Uv, Vv ; A-frag shared across both col-groups ----
    float nrm[2][4], inr[2][4];
    us4 pU[2][3];
    #pragma unroll
    for (int c = 0; c < 3; ++c) {
        f32x4 aU[2], aV[2];
        aU[0] = (f32x4){0.f,0.f,0.f,0.f}; aU[1] = (f32x4){0.f,0.f,0.f,0.f};
        aV[0] = (f32x4){0.f,0.f,0.f,0.f}; aV[1] = (f32x4){0.f,0.f,0.f,0.f};
        #pragma unroll
        for (int ks = 0; ks < 4; ++ks) {
            bf16x8 a = *(const bf16x8*)&SH[A1B + (c * TILE + l15) * A1S + (ks << 5) + (kp << 3)];
            #pragma unroll
            for (int g = 0; g < 2; ++g) {
                aU[g] = __builtin_amdgcn_mfma_f32_16x16x32_bf16(a, bU[g][ks], aU[g], 0, 0, 0);
                aV[g] = __builtin_amdgcn_mfma_f32_16x16x32_bf16(a, bV[g][ks], aV[g], 0, 0, 0);
            }
        }
        #pragma unroll
        for (int g = 0; g < 2; ++g) {
            us4 q;
            #pragma unroll
            for (int r = 0; r < 4; ++r) {
                float uu = aU[g][r], vv = aV[g][r];
                if (c == 0) { nrm[g][r] = vv * vv; inr[g][r] = uu * vv; }
                else        { nrm[g][r] += vv * vv; inr[g][r] += uu * vv; }
                q[r] = f2bf(uu);
            }
            pU[g][c] = q;
        }
    }
    #pragma unroll
    for (int r = 0; r < 4; ++r) {
        int row = (kp << 2) + r;
        SH[A2B + row * A2S + 128 + colA] = f2bf(nrm[0][r]);
        SH[A2B + row * A2S + 128 + colB] = f2bf(nrm[1][r]);
    }
    asm volatile("s_waitcnt lgkmcnt(0)" ::: "memory");
    __builtin_amdgcn_s_barrier();                         // B2: A2 complete

    // ---- stage 2: h = shifted_softplus(mlp_in @ w1.T + b1) ----
    f32x4 accH[2];
    accH[0] = (f32x4){0.f,0.f,0.f,0.f}; accH[1] = (f32x4){0.f,0.f,0.f,0.f};
    #pragma unroll
    for (int ks = 0; ks < 8; ++ks) {
        int k0 = (ks << 5) + (kp << 3);
        bf16x8 a = *(const bf16x8*)&SH[A2B + l15 * A2S + k0];
        #pragma unroll
        for (int g = 0; g < 2; ++g) {
            int colg = g ? colB : colA;
            bf16x8 bw;
            if constexpr (PRE) {
                bw = *(const bf16x8*)&wW1[colg * 256 + k0];
            } else {
                const float4* p = (const float4*)&aw1[colg * 256 + k0];
                bw = pack8(p[0], p[1]);
            }
            accH[g] = __builtin_amdgcn_mfma_f32_16x16x32_bf16(a, bw, accH[g], 0, 0, 0);
        }
    }
    {
        float b1A = ab1[colA], b1B = ab1[colB];
        #pragma unroll
        for (int r = 0; r < 4; ++r) {
            int row = (kp << 2) + r;
            float xA = accH[0][r] + b1A;
            float xB = accH[1][r] + b1B;
            float hA = fmaxf(xA, 0.f) + __logf(1.f + __expf(-fabsf(xA))) - 0.69314718056f;
            float hB = fmaxf(xB, 0.f) + __logf(1.f + __expf(-fabsf(xB))) - 0.69314718056f;
            SH[A3B + row * A3S + colA] = f2bf(hA);
            SH[A3B + row * A3S + colB] = f2bf(hB);
        }
    }
    asm volatile("s_waitcnt lgkmcnt(0)" ::: "memory");
    __builtin_amdgcn_s_barrier();                         // B3: A3 ready

    // ---- stage 3: three output GEMMs; A-frag shared across cg and j ----
    f32x4 accS[2], accT[2], accA[2];
    #pragma unroll
    for (int i = 0; i < 2; ++i) {
        accS[i] = (f32x4){0.f,0.f,0.f,0.f};
        accT[i] = (f32x4){0.f,0.f,0.f,0.f};
        accA[i] = (f32x4){0.f,0.f,0.f,0.f};
    }
    #pragma unroll
    for (int ks = 0; ks < 4; ++ks) {
        int k0 = (ks << 5) + (kp << 3);
        bf16x8 a = *(const bf16x8*)&SH[A3B + l15 * A3S + k0];
        #pragma unroll
        for (int g = 0; g < 2; ++g) {
            int colg = g ? colB : colA;
            bf16x8 bws, bwt, bwv;
            if constexpr (PRE) {
                bws = *(const bf16x8*)&wW2[(0 * F + colg) * F + k0];
                bwt = *(const bf16x8*)&wW2[(1 * F + colg) * F + k0];
                bwv = *(const bf16x8*)&wW2[(2 * F + colg) * F + k0];
            } else {
                const float4* p0 = (const float4*)&aw2[(size_t)(0 * F + colg) * F + k0];
                const float4* p1 = (const float4*)&aw2[(size_t)(1 * F + colg) * F + k0];
                const float4* p2 = (const float4*)&aw2[(size_t)(2 * F + colg) * F + k0];
                bws = pack8(p0[0], p0[1]);
                bwt = pack8(p1[0], p1[1]);
                bwv = pack8(p2[0], p2[1]);
            }
            accS[g] = __builtin_amdgcn_mfma_f32_16x16x32_bf16(a, bws, accS[g], 0, 0, 0);
            accT[g] = __builtin_amdgcn_mfma_f32_16x16x32_bf16(a, bwt, accT[g], 0, 0, 0);
            accA[g] = __builtin_amdgcn_mfma_f32_16x16x32_bf16(a, bwv, accA[g], 0, 0, 0);
        }
    }

    // ---- epilogue: v_new (dwordx3) and s_new; residuals from bf16 LDS ----
    #pragma unroll
    for (int g = 0; g < 2; ++g) {
        int colg = g ? colB : colA;
        float bss = ab2[colg];
        float bsv = ab2[F + colg];
        float bvv = ab2[2 * F + colg];
        #pragma unroll
        for (int r = 0; r < 4; ++r) {
            int nl = (kp << 2) + r;
            int n  = t * TILE + nl;
            float avv = accA[g][r] + bvv;
            size_t base = ((size_t)n * F + colg) * 3;
            f3 val;
            val.x = bf2f(SH[A1B + (0 * TILE + nl) * A1S + colg]) + avv * bf2f(pU[g][0][r]);
            val.y = bf2f(SH[A1B + (1 * TILE + nl) * A1S + colg]) + avv * bf2f(pU[g][1][r]);
            val.z = bf2f(SH[A1B + (2 * TILE + nl) * A1S + colg]) + avv * bf2f(pU[g][2][r]);
            *(f3*)&out[NF + base] = val;
            float sres = bf2f(SH[A2B + nl * A2S + colg]);
            out[(size_t)n * F + colg] = sres + (accS[g][r] + bss) + (accT[g][r] + bsv) * inr[g][r];
        }
    }
}

extern "C" void kernel_launch(void* const* d_in, const int* in_sizes, int n_in,
                              void* d_out, int out_size, void* d_ws, size_t ws_size,
                              hipStream_t stream) {
    (void)n_in; (void)out_size;
    const float* s   = (const float*)d_in[0];
    const float* v   = (const float*)d_in[1];
    const float* Uw  = (const float*)d_in[2];
    const float* Vw  = (const float*)d_in[3];
    const float* aw1 = (const float*)d_in[4];
    const float* ab1 = (const float*)d_in[5];
    const float* aw2 = (const float*)d_in[6];
    const float* ab2 = (const float*)d_in[7];
    float* out = (float*)d_out;
    int Ntot = in_sizes[0] / F;                 // 100000 (divisible by TILE=16)
    int NT   = Ntot / TILE;                     // 6250

    if (ws_size >= 114688u * sizeof(unsigned short)) {
        unsigned short* wbf = (unsigned short*)d_ws;
        hipLaunchKernelGGL(prep_w, dim3(112), dim3(256), 0, stream, Uw, Vw, aw1, aw2, wbf);
        hipLaunchKernelGGL((painn_main<true>), dim3(NT), dim3(NTHR), 0, stream,
                           s, v, Uw, Vw, aw1, ab1, aw2, ab2, wbf, out, Ntot);
    } else {
        hipLaunchKernelGGL((painn_main<false>), dim3(NT), dim3(NTHR), 0, stream,
                           s, v, Uw, Vw, aw1, ab1, aw2, ab2, (const unsigned short*)nullptr, out, Ntot);
    }
}